// Round 7
// baseline (654.857 us; speedup 1.0000x reference)
//
#include <hip/hip_runtime.h>
#include <hip/hip_bf16.h>

typedef __attribute__((ext_vector_type(8))) short bf16x8;
typedef __attribute__((ext_vector_type(4))) float f32x4;

#define MFMA16(a, b, c) __builtin_amdgcn_mfma_f32_16x16x32_bf16((a), (b), (c), 0, 0, 0)

typedef __attribute__((address_space(1))) const void gconst_t;
typedef __attribute__((address_space(3))) void lds_t;
__device__ __forceinline__ void gload16(const void* gp, void* lp) {
    __builtin_amdgcn_global_load_lds((gconst_t*)gp, (lds_t*)lp, 16, 0, 0);
}

#define BAR() asm volatile("s_barrier" ::: "memory")
#define VMCNT0() asm volatile("s_waitcnt vmcnt(0)" ::: "memory")
#define DRAIN() asm volatile("s_waitcnt vmcnt(0) lgkmcnt(0)" ::: "memory")
#define SCHED0() __builtin_amdgcn_sched_barrier(0)

// ---------------------------------------------------------------------------
// Transpose + cast fp32 -> bf16:  X tensors (R=2048, C=1024, z=4 batches),
// also writes the raw fp32 tile into the concat output's first 2048 channels.
// ---------------------------------------------------------------------------
__global__ void transpose_x(const float* __restrict__ in, __hip_bfloat16* __restrict__ out,
                            float* __restrict__ copy_out) {
    __shared__ float tile[32][33];
    int r0 = blockIdx.y * 32, c0 = blockIdx.x * 32;
    size_t zoff = (size_t)blockIdx.z * 2048 * 1024;
    const float* ib = in + zoff;
    __hip_bfloat16* ob = out + zoff;
    float* cb = copy_out + (size_t)blockIdx.z * 4194304;
    int tx = threadIdx.x, ty = threadIdx.y;
#pragma unroll
    for (int i = ty; i < 32; i += 8) {
        float v = ib[(size_t)(r0 + i) * 1024 + c0 + tx];
        tile[i][tx] = v;
        cb[(size_t)(r0 + i) * 1024 + c0 + tx] = v;
    }
    __syncthreads();
#pragma unroll
    for (int i = ty; i < 32; i += 8)
        ob[(size_t)(c0 + i) * 2048 + r0 + tx] = __float2bfloat16(tile[tx][i]);
}

// All four 2048x2048 weight transposes in one dispatch (z selects the matrix)
struct TArgs {
    const float* src[4];
    __hip_bfloat16* dst[4];
};
__global__ void transpose_w4(TArgs ta) {
    __shared__ float tile[32][33];
    const int z = blockIdx.z;
    const float* __restrict__ ib = ta.src[z];
    __hip_bfloat16* __restrict__ ob = ta.dst[z];
    int r0 = blockIdx.y * 32, c0 = blockIdx.x * 32;
    int tx = threadIdx.x, ty = threadIdx.y;
#pragma unroll
    for (int i = ty; i < 32; i += 8)
        tile[i][tx] = ib[(size_t)(r0 + i) * 2048 + c0 + tx];
    __syncthreads();
#pragma unroll
    for (int i = ty; i < 32; i += 8)
        ob[(size_t)(c0 + i) * 2048 + r0 + tx] = __float2bfloat16(tile[tx][i]);
}

// rel_emb (63x256 fp32) -> bf16 padded to 64 rows (row 63 = 0)
__global__ void conv_rel(const float* __restrict__ rel, __hip_bfloat16* __restrict__ relb) {
    int i = blockIdx.x * 256 + threadIdx.x;  // 64*256 = 16384
    if (i < 64 * 256) {
        int r = i >> 8;
        relb[i] = __float2bfloat16(r < 63 ? rel[i] : 0.f);
    }
}

// ---------------------------------------------------------------------------
// 256x256-tile, BK=64, 4-wave (2x2, wave tile 128x128) GEMM, 1 wave/SIMD.
// acc = 8x8 f32x4 = 256 AGPR; frags aE/aO (64+64 VGPR) + breg (16) ~= 170 VGPR
// -> fits 512-reg/wave budget at 1 wave/SIMD (launch_bounds(256,1)).
// Per K-tile: 128 MFMA/wave vs only 32 b128 reads/wave (2x reuse of round-4)
// -> per-CU LDS 1536 cyc < MFMA 2483 cyc.  Schedule: 8 nf-groups of
// [reads -> sched_barrier -> 16 MFMA]; MFMA exec backlog (310 cyc/group/SIMD)
// hides read drain + the mid-tile vmcnt gate.  A(t+1), B(t+1,nf0) pre-read
// during nf4..7 after [VMCNT0 ; BAR] publishes stage(t+1).
// ---------------------------------------------------------------------------
struct GArgs {
    const __hip_bfloat16* A[6];
    const __hip_bfloat16* B[6];
    void* C[6];
    const float* bias[6];
};

template <int MODE>
__global__ __launch_bounds__(256, 1) void gemm4w(GArgs ga, int N, int K,
                                                 float* __restrict__ dout) {
    __shared__ __align__(16) char smem[131072];

    // XCD-aware chunked swizzle (nwg % 8 == 0 for all our launches)
    const int gx = gridDim.x, gy = gridDim.y;
    int lid = blockIdx.x + gx * (blockIdx.y + gy * blockIdx.z);
    const int nwg = gx * gy * gridDim.z;
    int swz = (lid & 7) * (nwg >> 3) + (lid >> 3);
    const int z = swz / (gx * gy);
    int rem = swz - z * (gx * gy);
    const int by = rem / gx;
    const int bx = rem - by * gx;

    const __hip_bfloat16* __restrict__ A = ga.A[z];
    const __hip_bfloat16* __restrict__ B = ga.B[z];
    const float* __restrict__ bias = ga.bias[z];
    const int row0 = by * 256, col0 = bx * 256;

    const int tid = threadIdx.x;
    const int wave = tid >> 6, lane = tid & 63;
    const int l15 = lane & 15, lg = lane >> 4;
    const int wm = wave >> 1, wn = wave & 1;  // 2 x 2 wave grid, 128x128 per wave

    // staging lane constants (source pre-swizzled, LDS dest linear)
    const int srow = tid >> 3;               // 0..31: row within 32-row pass
    const int sch = (tid & 7) ^ (srow & 7);  // swizzled 16B chunk in row
    const int xr = (l15 & 7) << 4;           // read-side XOR

    f32x4 acc[8][8] = {};
    bf16x8 aE[8][2], aO[8][2], breg[2][2];

    const int NT = K >> 6;  // K-tiles (32)

    // stage full 256x64 A-tile + 256x64 B-tile (64KB) for K-tile T into buf o
    auto STAGE = [&](int T, int o) {
#pragma unroll
        for (int p = 0; p < 8; ++p) {
            gload16(A + (size_t)(row0 + p * 32 + srow) * K + T * 64 + sch * 8,
                    smem + o * 65536 + p * 4096 + wave * 1024);
            gload16(B + (size_t)(col0 + p * 32 + srow) * K + T * 64 + sch * 8,
                    smem + o * 65536 + 32768 + p * 4096 + wave * 1024);
        }
    };
    auto RDB = [&](bf16x8 (&dst)[2], int o, int nf) {
#pragma unroll
        for (int ks = 0; ks < 2; ++ks)
            dst[ks] = *(const bf16x8*)(smem + o * 65536 + 32768 +
                                       (wn * 128 + nf * 16 + l15) * 128 +
                                       ((ks * 64 + lg * 16) ^ xr));
    };
    auto RDA2 = [&](bf16x8 (&dst)[8][2], int o, int mf0) {
#pragma unroll
        for (int p = 0; p < 2; ++p)
#pragma unroll
            for (int ks = 0; ks < 2; ++ks)
                dst[mf0 + p][ks] = *(const bf16x8*)(smem + o * 65536 +
                                                    (wm * 128 + (mf0 + p) * 16 + l15) * 128 +
                                                    ((ks * 64 + lg * 16) ^ xr));
    };

#define MFMA_NF(AR, NF, B2)                                            \
    _Pragma("unroll") for (int mf = 0; mf < 8; ++mf) {                 \
        acc[mf][(NF)] = MFMA16(AR[mf][0], B2[0], acc[mf][(NF)]);       \
        acc[mf][(NF)] = MFMA16(AR[mf][1], B2[1], acc[mf][(NF)]);       \
    }

#define TILE(T, CB, ACUR, ANXT)                                               \
    {                                                                         \
        const int tn = ((T) + 1 < NT) ? (T) + 1 : (T);                        \
        STAGE(tn, (CB) ^ 1);                                                  \
        _Pragma("unroll") for (int nf = 0; nf < 4; ++nf) {                    \
            RDB(breg[(nf + 1) & 1], (CB), nf + 1);                            \
            SCHED0();                                                         \
            MFMA_NF(ACUR, nf, breg[nf & 1]);                                  \
        }                                                                     \
        VMCNT0(); /* own stage(t+1) drained */                                \
        BAR();    /* all waves' stage(t+1) visible; buf o readable */         \
        _Pragma("unroll") for (int nf = 4; nf < 8; ++nf) {                    \
            RDB(breg[(nf + 1) & 1], nf < 7 ? (CB) : ((CB) ^ 1), (nf + 1) & 7); \
            RDA2(ANXT, (CB) ^ 1, (nf - 4) * 2);                               \
            SCHED0();                                                         \
            MFMA_NF(ACUR, nf, breg[nf & 1]);                                  \
        }                                                                     \
        BAR(); /* buf CB dead -> next tile may re-stage it */                 \
    }

    // prologue: tile 0 staged + operands pre-read
    STAGE(0, 0);
    VMCNT0();
    BAR();
    RDA2(aE, 0, 0);
    RDA2(aE, 0, 2);
    RDA2(aE, 0, 4);
    RDA2(aE, 0, 6);
    RDB(breg[0], 0, 0);

#pragma unroll 1
    for (int t = 0; t < NT; t += 2) {
        TILE(t, 0, aE, aO);
        TILE(t + 1, 1, aO, aE);
    }
    DRAIN();  // tail re-stage + trailing reads before exit

    if (MODE == 0) {
        __hip_bfloat16* __restrict__ C = (__hip_bfloat16*)ga.C[z];
#pragma unroll
        for (int mf = 0; mf < 8; ++mf) {
            int m = row0 + wm * 128 + mf * 16 + lg * 4;
#pragma unroll
            for (int nf = 0; nf < 8; ++nf) {
                int n = col0 + wn * 128 + nf * 16 + l15;
                float bv = bias[n];
#pragma unroll
                for (int r = 0; r < 4; ++r)
                    C[(size_t)(m + r) * N + n] = __float2bfloat16(acc[mf][nf][r] + bv);
            }
        }
    } else {
        // rows = output channel n, cols = m = b*1024 + p (coalesced in p)
        float* __restrict__ OB = dout + (size_t)z * 16777216;
#pragma unroll
        for (int mf = 0; mf < 8; ++mf) {
            int n0 = row0 + wm * 128 + mf * 16 + lg * 4;
#pragma unroll
            for (int nf = 0; nf < 8; ++nf) {
                int m = col0 + wn * 128 + nf * 16 + l15;
                size_t base = (size_t)(m >> 10) * 4194304 + (size_t)(m & 1023);
#pragma unroll
                for (int r = 0; r < 4; ++r) {
                    int n = n0 + r;
                    OB[base + (size_t)(2048 + n) * 1024] = acc[mf][nf][r] + bias[n];
                }
            }
        }
    }
#undef MFMA_NF
#undef TILE
}

// ---------------------------------------------------------------------------
// Axial attention: one block per (dir, b, head, w).  Q,K,V row-major [4096][2048] bf16.
// ---------------------------------------------------------------------------
__global__ __launch_bounds__(256, 2) void attn_kernel(
    const __hip_bfloat16* __restrict__ Qa, const __hip_bfloat16* __restrict__ Ka,
    const __hip_bfloat16* __restrict__ Va, const __hip_bfloat16* __restrict__ Qb,
    const __hip_bfloat16* __restrict__ Kb, const __hip_bfloat16* __restrict__ Vb,
    const __hip_bfloat16* __restrict__ relb, __hip_bfloat16* __restrict__ Oa,
    __hip_bfloat16* __restrict__ Ob) {
    const int w = blockIdx.x;   // 0..31
    const int nh = blockIdx.y;  // 0..7
    const int zb = blockIdx.z;  // dir*4 + b
    const int dir = zb >> 2, b = zb & 3;
    const __hip_bfloat16* __restrict__ Q = dir ? Qb : Qa;
    const __hip_bfloat16* __restrict__ K = dir ? Kb : Ka;
    const __hip_bfloat16* __restrict__ V = dir ? Vb : Va;
    __hip_bfloat16* __restrict__ O = dir ? Ob : Oa;

    __shared__ __align__(16) __hip_bfloat16 vt[256 * 40];  // V^T, stride 40
    __shared__ float ssc[32 * 32];
    __shared__ float es[32 * 64];
    __shared__ __align__(16) __hip_bfloat16 ps[32 * 32];

    const int tid = threadIdx.x;
    const int lane = tid & 63, wave = tid >> 6;
    const int l15 = lane & 15, lg = lane >> 4;
    const int mt = wave >> 1, nt = wave & 1;

    const size_t rowbase = ((size_t)b * 1024 + w) * 2048 + (size_t)nh * 256;

    // stage V transposed: vt[c][hk]
    for (int i = 0; i < 32; ++i) {
        int e = i * 256 + tid;
        int hk = e >> 8, c = e & 255;
        vt[c * 40 + hk] = V[rowbase + (size_t)hk * 65536 + c];
    }

    f32x4 sacc = {}, e0 = {}, e1 = {};
#pragma unroll
    for (int k8 = 0; k8 < 256; k8 += 32) {
        bf16x8 af = *(const bf16x8*)&Q[rowbase + (size_t)(mt * 16 + l15) * 65536 + k8 + lg * 8];
        bf16x8 bf = *(const bf16x8*)&K[rowbase + (size_t)(nt * 16 + l15) * 65536 + k8 + lg * 8];
        bf16x8 r0 = *(const bf16x8*)&relb[(size_t)(nt * 32 + l15) * 256 + k8 + lg * 8];
        bf16x8 r1 = *(const bf16x8*)&relb[(size_t)(nt * 32 + 16 + l15) * 256 + k8 + lg * 8];
        sacc = MFMA16(af, bf, sacc);
        e0 = MFMA16(af, r0, e0);
        e1 = MFMA16(af, r1, e1);
    }
#pragma unroll
    for (int r = 0; r < 4; ++r) {
        int row = mt * 16 + lg * 4 + r;
        ssc[row * 32 + nt * 16 + l15] = sacc[r];
        es[row * 64 + nt * 32 + l15] = e0[r];
        es[row * 64 + nt * 32 + 16 + l15] = e1[r];
    }
    __syncthreads();

    {
        int h = tid >> 3, sub = tid & 7;
        float v4[4];
        float mx = -1e30f;
#pragma unroll
        for (int i = 0; i < 4; ++i) {
            int k = sub * 4 + i;
            int dh = k - h; if (dh < 0) dh += 63;
            int dw = k - w; if (dw < 0) dw += 63;
            float s = (ssc[h * 32 + k] + es[h * 64 + dh] + es[h * 64 + dw]) * 0.0625f;
            v4[i] = s;
            mx = fmaxf(mx, s);
        }
        mx = fmaxf(mx, __shfl_xor(mx, 1));
        mx = fmaxf(mx, __shfl_xor(mx, 2));
        mx = fmaxf(mx, __shfl_xor(mx, 4));
        float sum = 0.f;
#pragma unroll
        for (int i = 0; i < 4; ++i) {
            v4[i] = __expf(v4[i] - mx);
            sum += v4[i];
        }
        sum += __shfl_xor(sum, 1);
        sum += __shfl_xor(sum, 2);
        sum += __shfl_xor(sum, 4);
        float inv = 1.f / sum;
#pragma unroll
        for (int i = 0; i < 4; ++i) ps[h * 32 + sub * 4 + i] = __float2bfloat16(v4[i] * inv);
    }
    __syncthreads();

    bf16x8 paf = *(const bf16x8*)&ps[(mt * 16 + l15) * 32 + lg * 8];
#pragma unroll
    for (int j = 0; j < 8; ++j) {
        int ct = nt * 8 + j;  // 0..15
        bf16x8 bv = *(const bf16x8*)&vt[(size_t)(ct * 16 + l15) * 40 + lg * 8];
        f32x4 oacc = {};
        oacc = MFMA16(paf, bv, oacc);
#pragma unroll
        for (int r = 0; r < 4; ++r) {
            int hh = mt * 16 + lg * 4 + r;
            O[rowbase + (size_t)hh * 65536 + ct * 16 + l15] = __float2bfloat16(oacc[r]);
        }
    }
}

// ---------------------------------------------------------------------------
extern "C" void kernel_launch(void* const* d_in, const int* in_sizes, int n_in, void* d_out,
                              int out_size, void* d_ws, size_t ws_size, hipStream_t stream) {
    const float* Xl = (const float*)d_in[0];
    const float* Xr = (const float*)d_in[1];
    const float* Wq = (const float*)d_in[2];
    const float* bq = (const float*)d_in[3];
    const float* Wk = (const float*)d_in[4];
    const float* bk = (const float*)d_in[5];
    const float* Wv = (const float*)d_in[6];
    const float* bv = (const float*)d_in[7];
    const float* Wo = (const float*)d_in[8];
    const float* bo = (const float*)d_in[9];
    const float* rel = (const float*)d_in[10];
    float* out = (float*)d_out;

    char* ws = (char*)d_ws;
    size_t off = 0;
    auto nxt = [&](size_t bytes) {
        void* p = ws + off;
        off += bytes;
        return p;
    };
    __hip_bfloat16* Xbl = (__hip_bfloat16*)nxt(16777216);
    __hip_bfloat16* Xbr = (__hip_bfloat16*)nxt(16777216);
    __hip_bfloat16* Wtq = (__hip_bfloat16*)nxt(8388608);
    __hip_bfloat16* Wtk = (__hip_bfloat16*)nxt(8388608);
    __hip_bfloat16* Wtv = (__hip_bfloat16*)nxt(8388608);
    __hip_bfloat16* Wto = (__hip_bfloat16*)nxt(8388608);
    __hip_bfloat16* relb = (__hip_bfloat16*)nxt(32768);
    __hip_bfloat16* Ql = (__hip_bfloat16*)nxt(16777216);
    __hip_bfloat16* Kl = (__hip_bfloat16*)nxt(16777216);
    __hip_bfloat16* Vl = (__hip_bfloat16*)nxt(16777216);
    __hip_bfloat16* Qr = (__hip_bfloat16*)nxt(16777216);
    __hip_bfloat16* Kr = (__hip_bfloat16*)nxt(16777216);
    __hip_bfloat16* Vr = (__hip_bfloat16*)nxt(16777216);
    // att outputs alias the Xb buffers (Xb dead after phase-1 GEMM)
    __hip_bfloat16* At0 = Xbl;
    __hip_bfloat16* At1 = Xbr;

    dim3 tb(32, 8);
    // X transposes also emit the raw-feature fp32 copy into the concat output
    transpose_x<<<dim3(32, 64, 4), tb, 0, stream>>>(Xl, Xbl, out);
    transpose_x<<<dim3(32, 64, 4), tb, 0, stream>>>(Xr, Xbr, out + 16777216);
    TArgs tw;
    tw.src[0] = Wq; tw.src[1] = Wk; tw.src[2] = Wv; tw.src[3] = Wo;
    tw.dst[0] = Wtq; tw.dst[1] = Wtk; tw.dst[2] = Wtv; tw.dst[3] = Wto;
    transpose_w4<<<dim3(64, 64, 4), tb, 0, stream>>>(tw);
    conv_rel<<<64, 256, 0, stream>>>(rel, relb);

    GArgs g1 = {};
    g1.A[0] = Xbl; g1.A[1] = Xbl; g1.A[2] = Xbl;
    g1.A[3] = Xbr; g1.A[4] = Xbr; g1.A[5] = Xbr;
    g1.B[0] = Wtq; g1.B[1] = Wtk; g1.B[2] = Wtv;
    g1.B[3] = Wtq; g1.B[4] = Wtk; g1.B[5] = Wtv;
    g1.C[0] = Ql; g1.C[1] = Kl; g1.C[2] = Vl;
    g1.C[3] = Qr; g1.C[4] = Kr; g1.C[5] = Vr;
    g1.bias[0] = bq; g1.bias[1] = bk; g1.bias[2] = bv;
    g1.bias[3] = bq; g1.bias[4] = bk; g1.bias[5] = bv;
    // M=4096 (16 m-tiles), N=2048 (8 n-tiles), z=6 -> 768 blocks (3 full rounds)
    gemm4w<0><<<dim3(8, 16, 6), 256, 0, stream>>>(g1, 2048, 2048, nullptr);

    // dir0: weighted_r = attn(Q_l, K_r, V_r); dir1: weighted_l = attn(Q_r, K_l, V_l)
    attn_kernel<<<dim3(32, 8, 8), 256, 0, stream>>>(Ql, Kr, Vr, Qr, Kl, Vl, relb, At0, At1);

    // phase-2: operands swapped (A=Wo^T rows=n 2048, B=att rows=m 4096)
    GArgs g2 = {};
    g2.A[0] = Wto; g2.A[1] = Wto;
    g2.B[0] = At0; g2.B[1] = At1;
    g2.bias[0] = bo; g2.bias[1] = bo;
    gemm4w<1><<<dim3(16, 8, 2), 256, 0, stream>>>(g2, 2048, 2048, out);
}

// Round 8
// 394.336 us; speedup vs baseline: 1.6607x; 1.6607x over previous
//
#include <hip/hip_runtime.h>
#include <hip/hip_bf16.h>

typedef __attribute__((ext_vector_type(8))) short bf16x8;
typedef __attribute__((ext_vector_type(4))) float f32x4;

#define MFMA16(a, b, c) __builtin_amdgcn_mfma_f32_16x16x32_bf16((a), (b), (c), 0, 0, 0)

typedef __attribute__((address_space(1))) const void gconst_t;
typedef __attribute__((address_space(3))) void lds_t;
__device__ __forceinline__ void gload16(const void* gp, void* lp) {
    __builtin_amdgcn_global_load_lds((gconst_t*)gp, (lds_t*)lp, 16, 0, 0);
}

#define BAR() asm volatile("s_barrier" ::: "memory")
#define VMCNT0() asm volatile("s_waitcnt vmcnt(0)" ::: "memory")
#define PRIO1() __builtin_amdgcn_s_setprio(1)
#define PRIO0() __builtin_amdgcn_s_setprio(0)
#define SCHED0() __builtin_amdgcn_sched_barrier(0)

// ---------------------------------------------------------------------------
// Transpose + cast fp32 -> bf16:  X tensors (R=2048, C=1024, z=4 batches),
// also writes the raw fp32 tile into the concat output's first 2048 channels.
// ---------------------------------------------------------------------------
__global__ void transpose_x(const float* __restrict__ in, __hip_bfloat16* __restrict__ out,
                            float* __restrict__ copy_out) {
    __shared__ float tile[32][33];
    int r0 = blockIdx.y * 32, c0 = blockIdx.x * 32;
    size_t zoff = (size_t)blockIdx.z * 2048 * 1024;
    const float* ib = in + zoff;
    __hip_bfloat16* ob = out + zoff;
    float* cb = copy_out + (size_t)blockIdx.z * 4194304;
    int tx = threadIdx.x, ty = threadIdx.y;
#pragma unroll
    for (int i = ty; i < 32; i += 8) {
        float v = ib[(size_t)(r0 + i) * 1024 + c0 + tx];
        tile[i][tx] = v;
        cb[(size_t)(r0 + i) * 1024 + c0 + tx] = v;
    }
    __syncthreads();
#pragma unroll
    for (int i = ty; i < 32; i += 8)
        ob[(size_t)(c0 + i) * 2048 + r0 + tx] = __float2bfloat16(tile[tx][i]);
}

// All four 2048x2048 weight transposes in one dispatch (z selects the matrix)
struct TArgs {
    const float* src[4];
    __hip_bfloat16* dst[4];
};
__global__ void transpose_w4(TArgs ta) {
    __shared__ float tile[32][33];
    const int z = blockIdx.z;
    const float* __restrict__ ib = ta.src[z];
    __hip_bfloat16* __restrict__ ob = ta.dst[z];
    int r0 = blockIdx.y * 32, c0 = blockIdx.x * 32;
    int tx = threadIdx.x, ty = threadIdx.y;
#pragma unroll
    for (int i = ty; i < 32; i += 8)
        tile[i][tx] = ib[(size_t)(r0 + i) * 2048 + c0 + tx];
    __syncthreads();
#pragma unroll
    for (int i = ty; i < 32; i += 8)
        ob[(size_t)(c0 + i) * 2048 + r0 + tx] = __float2bfloat16(tile[tx][i]);
}

// rel_emb (63x256 fp32) -> bf16 padded to 64 rows (row 63 = 0)
__global__ void conv_rel(const float* __restrict__ rel, __hip_bfloat16* __restrict__ relb) {
    int i = blockIdx.x * 256 + threadIdx.x;  // 64*256 = 16384
    if (i < 64 * 256) {
        int r = i >> 8;
        relb[i] = __float2bfloat16(r < 63 ? rel[i] : 0.f);
    }
}

// ---------------------------------------------------------------------------
// 128x256-tile, BK=32, 8-wave (2x4, wave tile 64x64) GEMM, 2 blocks/CU.
// Inter-BLOCK skew (independent barriers) overlaps one block's LDS reads with
// the other's MFMA/barriers — the overlap barrier-locked waves can't provide.
// Regs/wave ~126 (acc 64 in AGPR + ~62 VGPR) -> 4 waves/SIMD (512-reg pool).
// LDS 2 x 24KB; 64B rows with chunk ^= (r&3)^((r>>2)&3) swizzle (uniform
// 2-per-bank-group = free); inverse pre-applied to global source (rule #21).
// Window: [STAGE(t+1) first (drains across window) | 8 ds_reads | 16 MFMA |
// vmcnt(0) | bar].  Stage targets the buffer whose readers all completed
// before the barrier preceding the stage.  Tail re-stage idempotent.
// ---------------------------------------------------------------------------
struct GArgs {
    const __hip_bfloat16* A[6];
    const __hip_bfloat16* B[6];
    void* C[6];
    const float* bias[6];
};

template <int MODE>
__global__ __launch_bounds__(512, 4) void gemmS(GArgs ga, int N, int K,
                                                float* __restrict__ dout) {
    __shared__ __align__(16) char smem[49152];

    // XCD-aware chunked swizzle (nwg % 8 == 0 for all our launches)
    const int gx = gridDim.x, gy = gridDim.y;
    int lid = blockIdx.x + gx * (blockIdx.y + gy * blockIdx.z);
    const int nwg = gx * gy * gridDim.z;
    int swz = (lid & 7) * (nwg >> 3) + (lid >> 3);
    const int z = swz / (gx * gy);
    int rem = swz - z * (gx * gy);
    const int by = rem / gx;
    const int bx = rem - by * gx;

    const __hip_bfloat16* __restrict__ A = ga.A[z];
    const __hip_bfloat16* __restrict__ B = ga.B[z];
    const float* __restrict__ bias = ga.bias[z];
    const int row0 = by * 128, col0 = bx * 256;

    const int tid = threadIdx.x;
    const int wave = tid >> 6, lane = tid & 63;
    const int l15 = lane & 15, lg = lane >> 4;
    const int wm = wave >> 2, wn = wave & 3;  // 2 x 4 grid of 64x64 tiles

    // staging constants: thread loads 16B; LDS dest linear tid*16; source
    // chunk pre-swizzled by the same involution used on reads
    const int srow = tid >> 2;                                 // 0..127
    const int sch = (tid & 3) ^ (srow & 3) ^ ((srow >> 2) & 3);  // chunk 0..3
    // read-side: byte chunk within 64B row (depends only on lane)
    const int rch = ((lg ^ (l15 & 3) ^ ((l15 >> 2) & 3)) << 4);
    const int abase = (wm * 64 + l15) * 64 + rch;         // + mf*1024
    const int bbase = 8192 + (wn * 64 + l15) * 64 + rch;  // + nf*1024

    f32x4 acc[4][4] = {};
    bf16x8 a[4], b[4];

    const int NT = K >> 5;  // 64 K-steps

    auto STAGE = [&](int T, int o) {
        gload16(A + (size_t)(row0 + srow) * K + T * 32 + sch * 8,
                smem + o * 24576 + tid * 16);
#pragma unroll
        for (int p = 0; p < 2; ++p)
            gload16(B + (size_t)(col0 + p * 128 + srow) * K + T * 32 + sch * 8,
                    smem + o * 24576 + 8192 + p * 8192 + tid * 16);
    };
    auto RD = [&](int o) {
#pragma unroll
        for (int mf = 0; mf < 4; ++mf)
            a[mf] = *(const bf16x8*)(smem + o * 24576 + abase + mf * 1024);
#pragma unroll
        for (int nf = 0; nf < 4; ++nf)
            b[nf] = *(const bf16x8*)(smem + o * 24576 + bbase + nf * 1024);
    };

#define MLOOP()                                              \
    PRIO1();                                                 \
    _Pragma("unroll") for (int mf = 0; mf < 4; ++mf)         \
    _Pragma("unroll") for (int nf = 0; nf < 4; ++nf)         \
        acc[mf][nf] = MFMA16(a[mf], b[nf], acc[mf][nf]);     \
    PRIO0();

    // prologue
    STAGE(0, 0);
    VMCNT0();
    BAR();

#pragma unroll 1
    for (int t = 0; t < NT; t += 2) {
        // window t (buf0): stage t+1 -> buf1 (readers of buf1 done last window)
        STAGE(t + 1, 1);
        RD(0);
        SCHED0();
        MLOOP();
        VMCNT0();
        BAR();
        // window t+1 (buf1): stage t+2 -> buf0 (tail: re-stage t+1, idempotent)
        STAGE((t + 2 < NT) ? t + 2 : t + 1, 0);
        RD(1);
        SCHED0();
        MLOOP();
        VMCNT0();
        BAR();
    }

    if (MODE == 0) {
        __hip_bfloat16* __restrict__ C = (__hip_bfloat16*)ga.C[z];
#pragma unroll
        for (int mf = 0; mf < 4; ++mf) {
            int m = row0 + wm * 64 + mf * 16 + lg * 4;
#pragma unroll
            for (int nf = 0; nf < 4; ++nf) {
                int n = col0 + wn * 64 + nf * 16 + l15;
                float bv = bias[n];
#pragma unroll
                for (int r = 0; r < 4; ++r)
                    C[(size_t)(m + r) * N + n] = __float2bfloat16(acc[mf][nf][r] + bv);
            }
        }
    } else {
        // rows = output channel n, cols = m = b*1024 + p (coalesced in p)
        float* __restrict__ OB = dout + (size_t)z * 16777216;
#pragma unroll
        for (int mf = 0; mf < 4; ++mf) {
            int n0 = row0 + wm * 64 + mf * 16 + lg * 4;
#pragma unroll
            for (int nf = 0; nf < 4; ++nf) {
                int m = col0 + wn * 64 + nf * 16 + l15;
                size_t base = (size_t)(m >> 10) * 4194304 + (size_t)(m & 1023);
#pragma unroll
                for (int r = 0; r < 4; ++r) {
                    int n = n0 + r;
                    OB[base + (size_t)(2048 + n) * 1024] = acc[mf][nf][r] + bias[n];
                }
            }
        }
    }
#undef MLOOP
}

// ---------------------------------------------------------------------------
// Axial attention: one block per (dir, b, head, w).  Q,K,V row-major [4096][2048] bf16.
// ---------------------------------------------------------------------------
__global__ __launch_bounds__(256, 2) void attn_kernel(
    const __hip_bfloat16* __restrict__ Qa, const __hip_bfloat16* __restrict__ Ka,
    const __hip_bfloat16* __restrict__ Va, const __hip_bfloat16* __restrict__ Qb,
    const __hip_bfloat16* __restrict__ Kb, const __hip_bfloat16* __restrict__ Vb,
    const __hip_bfloat16* __restrict__ relb, __hip_bfloat16* __restrict__ Oa,
    __hip_bfloat16* __restrict__ Ob) {
    const int w = blockIdx.x;   // 0..31
    const int nh = blockIdx.y;  // 0..7
    const int zb = blockIdx.z;  // dir*4 + b
    const int dir = zb >> 2, b = zb & 3;
    const __hip_bfloat16* __restrict__ Q = dir ? Qb : Qa;
    const __hip_bfloat16* __restrict__ K = dir ? Kb : Ka;
    const __hip_bfloat16* __restrict__ V = dir ? Vb : Va;
    __hip_bfloat16* __restrict__ O = dir ? Ob : Oa;

    __shared__ __align__(16) __hip_bfloat16 vt[256 * 40];  // V^T, stride 40
    __shared__ float ssc[32 * 32];
    __shared__ float es[32 * 64];
    __shared__ __align__(16) __hip_bfloat16 ps[32 * 32];

    const int tid = threadIdx.x;
    const int lane = tid & 63, wave = tid >> 6;
    const int l15 = lane & 15, lg = lane >> 4;
    const int mt = wave >> 1, nt = wave & 1;

    const size_t rowbase = ((size_t)b * 1024 + w) * 2048 + (size_t)nh * 256;

    // stage V transposed: vt[c][hk]
    for (int i = 0; i < 32; ++i) {
        int e = i * 256 + tid;
        int hk = e >> 8, c = e & 255;
        vt[c * 40 + hk] = V[rowbase + (size_t)hk * 65536 + c];
    }

    f32x4 sacc = {}, e0 = {}, e1 = {};
#pragma unroll
    for (int k8 = 0; k8 < 256; k8 += 32) {
        bf16x8 af = *(const bf16x8*)&Q[rowbase + (size_t)(mt * 16 + l15) * 65536 + k8 + lg * 8];
        bf16x8 bf = *(const bf16x8*)&K[rowbase + (size_t)(nt * 16 + l15) * 65536 + k8 + lg * 8];
        bf16x8 r0 = *(const bf16x8*)&relb[(size_t)(nt * 32 + l15) * 256 + k8 + lg * 8];
        bf16x8 r1 = *(const bf16x8*)&relb[(size_t)(nt * 32 + 16 + l15) * 256 + k8 + lg * 8];
        sacc = MFMA16(af, bf, sacc);
        e0 = MFMA16(af, r0, e0);
        e1 = MFMA16(af, r1, e1);
    }
#pragma unroll
    for (int r = 0; r < 4; ++r) {
        int row = mt * 16 + lg * 4 + r;
        ssc[row * 32 + nt * 16 + l15] = sacc[r];
        es[row * 64 + nt * 32 + l15] = e0[r];
        es[row * 64 + nt * 32 + 16 + l15] = e1[r];
    }
    __syncthreads();

    {
        int h = tid >> 3, sub = tid & 7;
        float v4[4];
        float mx = -1e30f;
#pragma unroll
        for (int i = 0; i < 4; ++i) {
            int k = sub * 4 + i;
            int dh = k - h; if (dh < 0) dh += 63;
            int dw = k - w; if (dw < 0) dw += 63;
            float s = (ssc[h * 32 + k] + es[h * 64 + dh] + es[h * 64 + dw]) * 0.0625f;
            v4[i] = s;
            mx = fmaxf(mx, s);
        }
        mx = fmaxf(mx, __shfl_xor(mx, 1));
        mx = fmaxf(mx, __shfl_xor(mx, 2));
        mx = fmaxf(mx, __shfl_xor(mx, 4));
        float sum = 0.f;
#pragma unroll
        for (int i = 0; i < 4; ++i) {
            v4[i] = __expf(v4[i] - mx);
            sum += v4[i];
        }
        sum += __shfl_xor(sum, 1);
        sum += __shfl_xor(sum, 2);
        sum += __shfl_xor(sum, 4);
        float inv = 1.f / sum;
#pragma unroll
        for (int i = 0; i < 4; ++i) ps[h * 32 + sub * 4 + i] = __float2bfloat16(v4[i] * inv);
    }
    __syncthreads();

    bf16x8 paf = *(const bf16x8*)&ps[(mt * 16 + l15) * 32 + lg * 8];
#pragma unroll
    for (int j = 0; j < 8; ++j) {
        int ct = nt * 8 + j;  // 0..15
        bf16x8 bv = *(const bf16x8*)&vt[(size_t)(ct * 16 + l15) * 40 + lg * 8];
        f32x4 oacc = {};
        oacc = MFMA16(paf, bv, oacc);
#pragma unroll
        for (int r = 0; r < 4; ++r) {
            int hh = mt * 16 + lg * 4 + r;
            O[rowbase + (size_t)hh * 65536 + ct * 16 + l15] = __float2bfloat16(oacc[r]);
        }
    }
}

// ---------------------------------------------------------------------------
extern "C" void kernel_launch(void* const* d_in, const int* in_sizes, int n_in, void* d_out,
                              int out_size, void* d_ws, size_t ws_size, hipStream_t stream) {
    const float* Xl = (const float*)d_in[0];
    const float* Xr = (const float*)d_in[1];
    const float* Wq = (const float*)d_in[2];
    const float* bq = (const float*)d_in[3];
    const float* Wk = (const float*)d_in[4];
    const float* bk = (const float*)d_in[5];
    const float* Wv = (const float*)d_in[6];
    const float* bv = (const float*)d_in[7];
    const float* Wo = (const float*)d_in[8];
    const float* bo = (const float*)d_in[9];
    const float* rel = (const float*)d_in[10];
    float* out = (float*)d_out;

    char* ws = (char*)d_ws;
    size_t off = 0;
    auto nxt = [&](size_t bytes) {
        void* p = ws + off;
        off += bytes;
        return p;
    };
    __hip_bfloat16* Xbl = (__hip_bfloat16*)nxt(16777216);
    __hip_bfloat16* Xbr = (__hip_bfloat16*)nxt(16777216);
    __hip_bfloat16* Wtq = (__hip_bfloat16*)nxt(8388608);
    __hip_bfloat16* Wtk = (__hip_bfloat16*)nxt(8388608);
    __hip_bfloat16* Wtv = (__hip_bfloat16*)nxt(8388608);
    __hip_bfloat16* Wto = (__hip_bfloat16*)nxt(8388608);
    __hip_bfloat16* relb = (__hip_bfloat16*)nxt(32768);
    __hip_bfloat16* Ql = (__hip_bfloat16*)nxt(16777216);
    __hip_bfloat16* Kl = (__hip_bfloat16*)nxt(16777216);
    __hip_bfloat16* Vl = (__hip_bfloat16*)nxt(16777216);
    __hip_bfloat16* Qr = (__hip_bfloat16*)nxt(16777216);
    __hip_bfloat16* Kr = (__hip_bfloat16*)nxt(16777216);
    __hip_bfloat16* Vr = (__hip_bfloat16*)nxt(16777216);
    // att outputs alias the Xb buffers (Xb dead after phase-1 GEMM)
    __hip_bfloat16* At0 = Xbl;
    __hip_bfloat16* At1 = Xbr;

    dim3 tb(32, 8);
    // X transposes also emit the raw-feature fp32 copy into the concat output
    transpose_x<<<dim3(32, 64, 4), tb, 0, stream>>>(Xl, Xbl, out);
    transpose_x<<<dim3(32, 64, 4), tb, 0, stream>>>(Xr, Xbr, out + 16777216);
    TArgs tw;
    tw.src[0] = Wq; tw.src[1] = Wk; tw.src[2] = Wv; tw.src[3] = Wo;
    tw.dst[0] = Wtq; tw.dst[1] = Wtk; tw.dst[2] = Wtv; tw.dst[3] = Wto;
    transpose_w4<<<dim3(64, 64, 4), tb, 0, stream>>>(tw);
    conv_rel<<<64, 256, 0, stream>>>(rel, relb);

    GArgs g1 = {};
    g1.A[0] = Xbl; g1.A[1] = Xbl; g1.A[2] = Xbl;
    g1.A[3] = Xbr; g1.A[4] = Xbr; g1.A[5] = Xbr;
    g1.B[0] = Wtq; g1.B[1] = Wtk; g1.B[2] = Wtv;
    g1.B[3] = Wtq; g1.B[4] = Wtk; g1.B[5] = Wtv;
    g1.C[0] = Ql; g1.C[1] = Kl; g1.C[2] = Vl;
    g1.C[3] = Qr; g1.C[4] = Kr; g1.C[5] = Vr;
    g1.bias[0] = bq; g1.bias[1] = bk; g1.bias[2] = bv;
    g1.bias[3] = bq; g1.bias[4] = bk; g1.bias[5] = bv;
    // M=4096/128=32, N=2048/256=8, z=6 -> 1536 blocks (3 rounds at 2/CU)
    gemmS<0><<<dim3(8, 32, 6), 512, 0, stream>>>(g1, 2048, 2048, nullptr);

    // dir0: weighted_r = attn(Q_l, K_r, V_r); dir1: weighted_l = attn(Q_r, K_l, V_l)
    attn_kernel<<<dim3(32, 8, 8), 256, 0, stream>>>(Ql, Kr, Vr, Qr, Kl, Vl, relb, At0, At1);

    // phase-2: operands swapped (A=Wo^T rows=n 2048, B=att rows=m 4096)
    GArgs g2 = {};
    g2.A[0] = Wto; g2.A[1] = Wto;
    g2.B[0] = At0; g2.B[1] = At1;
    g2.bias[0] = bo; g2.bias[1] = bo;
    gemmS<1><<<dim3(16, 16, 2), 512, 0, stream>>>(g2, 2048, 2048, out);
}

// Round 9
// 369.880 us; speedup vs baseline: 1.7705x; 1.0661x over previous
//
#include <hip/hip_runtime.h>
#include <hip/hip_bf16.h>

typedef __attribute__((ext_vector_type(8))) short bf16x8;
typedef __attribute__((ext_vector_type(4))) float f32x4;

#define MFMA16(a, b, c) __builtin_amdgcn_mfma_f32_16x16x32_bf16((a), (b), (c), 0, 0, 0)

typedef __attribute__((address_space(1))) const void gconst_t;
typedef __attribute__((address_space(3))) void lds_t;
__device__ __forceinline__ void gload16(const void* gp, void* lp) {
    __builtin_amdgcn_global_load_lds((gconst_t*)gp, (lds_t*)lp, 16, 0, 0);
}

#define BAR() asm volatile("s_barrier" ::: "memory")
#define VMCNT0() asm volatile("s_waitcnt vmcnt(0)" ::: "memory")
#define PRIO1() __builtin_amdgcn_s_setprio(1)
#define PRIO0() __builtin_amdgcn_s_setprio(0)
#define SCHED0() __builtin_amdgcn_sched_barrier(0)

// ---------------------------------------------------------------------------
// Transpose + cast fp32 -> bf16:  X tensors (R=2048, C=1024, z=4 batches),
// also writes the raw fp32 tile into the concat output's first 2048 channels.
// ---------------------------------------------------------------------------
__global__ void transpose_x(const float* __restrict__ in, __hip_bfloat16* __restrict__ out,
                            float* __restrict__ copy_out) {
    __shared__ float tile[32][33];
    int r0 = blockIdx.y * 32, c0 = blockIdx.x * 32;
    size_t zoff = (size_t)blockIdx.z * 2048 * 1024;
    const float* ib = in + zoff;
    __hip_bfloat16* ob = out + zoff;
    float* cb = copy_out + (size_t)blockIdx.z * 4194304;
    int tx = threadIdx.x, ty = threadIdx.y;
#pragma unroll
    for (int i = ty; i < 32; i += 8) {
        float v = ib[(size_t)(r0 + i) * 1024 + c0 + tx];
        tile[i][tx] = v;
        cb[(size_t)(r0 + i) * 1024 + c0 + tx] = v;
    }
    __syncthreads();
#pragma unroll
    for (int i = ty; i < 32; i += 8)
        ob[(size_t)(c0 + i) * 2048 + r0 + tx] = __float2bfloat16(tile[tx][i]);
}

// All four 2048x2048 weight transposes in one dispatch (z selects the matrix)
struct TArgs {
    const float* src[4];
    __hip_bfloat16* dst[4];
};
__global__ void transpose_w4(TArgs ta) {
    __shared__ float tile[32][33];
    const int z = blockIdx.z;
    const float* __restrict__ ib = ta.src[z];
    __hip_bfloat16* __restrict__ ob = ta.dst[z];
    int r0 = blockIdx.y * 32, c0 = blockIdx.x * 32;
    int tx = threadIdx.x, ty = threadIdx.y;
#pragma unroll
    for (int i = ty; i < 32; i += 8)
        tile[i][tx] = ib[(size_t)(r0 + i) * 2048 + c0 + tx];
    __syncthreads();
#pragma unroll
    for (int i = ty; i < 32; i += 8)
        ob[(size_t)(c0 + i) * 2048 + r0 + tx] = __float2bfloat16(tile[tx][i]);
}

// rel_emb (63x256 fp32) -> bf16 padded to 64 rows (row 63 = 0)
__global__ void conv_rel(const float* __restrict__ rel, __hip_bfloat16* __restrict__ relb) {
    int i = blockIdx.x * 256 + threadIdx.x;  // 64*256 = 16384
    if (i < 64 * 256) {
        int r = i >> 8;
        relb[i] = __float2bfloat16(r < 63 ? rel[i] : 0.f);
    }
}

// ---------------------------------------------------------------------------
// 256(M)x128(N) tile, BK=64, 4 waves (2x2, wave tile 128x64), 2 blocks/CU.
// LDS 80KB: A double-buffered (2 x 32KB) + B single-buffered (16KB).
// 128B rows with the PROVEN zero-conflict XOR swizzle (chunk ^= l15&7 on read,
// inverse pre-applied to global source; LDS dest linear — rule #21).
// Window t: [read B(t) + A-lo(t) | BAR1 | stage A(t+1)->alt + B(t+1) |
//   MFMA-lo ∥ read A-hi(t) | MFMA-hi | VMCNT0 | BAR2].
// B single-buffer safety: B(t) frags register-captured before BAR1; stage
// B(t+1) after BAR1. A buf o overwritten only in window t+1 (after BAR2(t)).
// Inter-block overlap (2 independent blocks/CU) covers intra-block stalls.
// Regs: acc 128 (AGPR) + frags 64 + addr ~30 -> fits 256/wave at 2 waves/SIMD.
// ---------------------------------------------------------------------------
struct GArgs {
    const __hip_bfloat16* A[6];
    const __hip_bfloat16* B[6];
    void* C[6];
    const float* bias[6];
};

template <int MODE>
__global__ __launch_bounds__(256, 2) void gemmS(GArgs ga, int N, int K,
                                                float* __restrict__ dout) {
    __shared__ __align__(16) char smem[81920];

    // XCD-aware chunked swizzle (nwg % 8 == 0 for all our launches)
    const int gx = gridDim.x, gy = gridDim.y;
    int lid = blockIdx.x + gx * (blockIdx.y + gy * blockIdx.z);
    const int nwg = gx * gy * gridDim.z;
    int swz = (lid & 7) * (nwg >> 3) + (lid >> 3);
    const int z = swz / (gx * gy);
    int rem = swz - z * (gx * gy);
    const int by = rem / gx;
    const int bx = rem - by * gx;

    const __hip_bfloat16* __restrict__ A = ga.A[z];
    const __hip_bfloat16* __restrict__ B = ga.B[z];
    const float* __restrict__ bias = ga.bias[z];
    const int row0 = by * 256, col0 = bx * 128;

    const int tid = threadIdx.x;
    const int wave = tid >> 6, lane = tid & 63;
    const int l15 = lane & 15, lg = lane >> 4;
    const int wm = wave >> 1, wn = wave & 1;  // 2x2 grid of 128x64 wave tiles

    // staging: thread loads 16B; LDS dest linear tid*16 (+pass*4096);
    // source chunk pre-swizzled by the read involution (row&7 == (tid>>3)&7)
    const int srow = tid >> 3;                      // row within 32-row pass
    const int sch = (tid & 7) ^ ((tid >> 3) & 7);   // source 16B chunk
    // read-side XOR (proven zero-conflict, round 3/4)
    const int xr = (l15 & 7) << 4;
    const int off0 = (lg * 16) ^ xr;       // ks=0 byte offset in 128B row
    const int off1 = (64 + lg * 16) ^ xr;  // ks=1

    f32x4 acc[8][4] = {};
    bf16x8 a[4][2], b[4][2];

    const int NT = K >> 6;  // 32 K-tiles

    auto STAGE_A = [&](int T, int o) {
#pragma unroll
        for (int p = 0; p < 8; ++p)
            gload16(A + (size_t)(row0 + p * 32 + srow) * K + T * 64 + sch * 8,
                    smem + o * 32768 + p * 4096 + tid * 16);
    };
    auto STAGE_B = [&](int T) {
#pragma unroll
        for (int p = 0; p < 4; ++p)
            gload16(B + (size_t)(col0 + p * 32 + srow) * K + T * 64 + sch * 8,
                    smem + 65536 + p * 4096 + tid * 16);
    };
    auto RDA = [&](int o, int mf0) {
#pragma unroll
        for (int p = 0; p < 4; ++p) {
            int row = wm * 128 + (mf0 + p) * 16 + l15;
            a[p][0] = *(const bf16x8*)(smem + o * 32768 + row * 128 + off0);
            a[p][1] = *(const bf16x8*)(smem + o * 32768 + row * 128 + off1);
        }
    };
    auto RDB = [&]() {
#pragma unroll
        for (int nf = 0; nf < 4; ++nf) {
            int row = wn * 64 + nf * 16 + l15;
            b[nf][0] = *(const bf16x8*)(smem + 65536 + row * 128 + off0);
            b[nf][1] = *(const bf16x8*)(smem + 65536 + row * 128 + off1);
        }
    };

#define MHALF(MOFF)                                                        \
    PRIO1();                                                               \
    _Pragma("unroll") for (int p = 0; p < 4; ++p)                          \
    _Pragma("unroll") for (int nf = 0; nf < 4; ++nf) {                     \
        acc[(MOFF) + p][nf] = MFMA16(a[p][0], b[nf][0], acc[(MOFF) + p][nf]); \
        acc[(MOFF) + p][nf] = MFMA16(a[p][1], b[nf][1], acc[(MOFF) + p][nf]); \
    }                                                                      \
    PRIO0();

#define WINDOW(T, O)                                          \
    {                                                         \
        const int tn = ((T) + 1 < NT) ? (T) + 1 : (T);        \
        RDB();                                                \
        RDA((O), 0);                                          \
        BAR(); /* B(t) frags captured by all waves */         \
        STAGE_A(tn, (O) ^ 1);                                 \
        STAGE_B(tn);                                          \
        SCHED0();                                             \
        MHALF(0);                                             \
        RDA((O), 4);                                          \
        SCHED0();                                             \
        MHALF(4);                                             \
        VMCNT0();                                             \
        BAR(); /* stages published; buf (O) dead */           \
    }

    // prologue
    STAGE_A(0, 0);
    STAGE_B(0);
    VMCNT0();
    BAR();

#pragma unroll 1
    for (int t = 0; t < NT; t += 2) {
        WINDOW(t, 0);
        WINDOW(t + 1, 1);
    }

    if (MODE == 0) {
        __hip_bfloat16* __restrict__ C = (__hip_bfloat16*)ga.C[z];
#pragma unroll
        for (int mf = 0; mf < 8; ++mf) {
            int m = row0 + wm * 128 + mf * 16 + lg * 4;
#pragma unroll
            for (int nf = 0; nf < 4; ++nf) {
                int n = col0 + wn * 64 + nf * 16 + l15;
                float bv = bias[n];
#pragma unroll
                for (int r = 0; r < 4; ++r)
                    C[(size_t)(m + r) * N + n] = __float2bfloat16(acc[mf][nf][r] + bv);
            }
        }
    } else {
        // rows = output channel n, cols = m = b*1024 + p (coalesced in p)
        float* __restrict__ OB = dout + (size_t)z * 16777216;
#pragma unroll
        for (int mf = 0; mf < 8; ++mf) {
            int n0 = row0 + wm * 128 + mf * 16 + lg * 4;
#pragma unroll
            for (int nf = 0; nf < 4; ++nf) {
                int m = col0 + wn * 64 + nf * 16 + l15;
                size_t base = (size_t)(m >> 10) * 4194304 + (size_t)(m & 1023);
#pragma unroll
                for (int r = 0; r < 4; ++r) {
                    int n = n0 + r;
                    OB[base + (size_t)(2048 + n) * 1024] = acc[mf][nf][r] + bias[n];
                }
            }
        }
    }
#undef MHALF
#undef WINDOW
}

// ---------------------------------------------------------------------------
// Axial attention: one block per (dir, b, head, w).  Q,K,V row-major [4096][2048] bf16.
// ---------------------------------------------------------------------------
__global__ __launch_bounds__(256, 2) void attn_kernel(
    const __hip_bfloat16* __restrict__ Qa, const __hip_bfloat16* __restrict__ Ka,
    const __hip_bfloat16* __restrict__ Va, const __hip_bfloat16* __restrict__ Qb,
    const __hip_bfloat16* __restrict__ Kb, const __hip_bfloat16* __restrict__ Vb,
    const __hip_bfloat16* __restrict__ relb, __hip_bfloat16* __restrict__ Oa,
    __hip_bfloat16* __restrict__ Ob) {
    const int w = blockIdx.x;   // 0..31
    const int nh = blockIdx.y;  // 0..7
    const int zb = blockIdx.z;  // dir*4 + b
    const int dir = zb >> 2, b = zb & 3;
    const __hip_bfloat16* __restrict__ Q = dir ? Qb : Qa;
    const __hip_bfloat16* __restrict__ K = dir ? Kb : Ka;
    const __hip_bfloat16* __restrict__ V = dir ? Vb : Va;
    __hip_bfloat16* __restrict__ O = dir ? Ob : Oa;

    __shared__ __align__(16) __hip_bfloat16 vt[256 * 40];  // V^T, stride 40
    __shared__ float ssc[32 * 32];
    __shared__ float es[32 * 64];
    __shared__ __align__(16) __hip_bfloat16 ps[32 * 32];

    const int tid = threadIdx.x;
    const int lane = tid & 63, wave = tid >> 6;
    const int l15 = lane & 15, lg = lane >> 4;
    const int mt = wave >> 1, nt = wave & 1;

    const size_t rowbase = ((size_t)b * 1024 + w) * 2048 + (size_t)nh * 256;

    // stage V transposed: vt[c][hk]
    for (int i = 0; i < 32; ++i) {
        int e = i * 256 + tid;
        int hk = e >> 8, c = e & 255;
        vt[c * 40 + hk] = V[rowbase + (size_t)hk * 65536 + c];
    }

    f32x4 sacc = {}, e0 = {}, e1 = {};
#pragma unroll
    for (int k8 = 0; k8 < 256; k8 += 32) {
        bf16x8 af = *(const bf16x8*)&Q[rowbase + (size_t)(mt * 16 + l15) * 65536 + k8 + lg * 8];
        bf16x8 bf = *(const bf16x8*)&K[rowbase + (size_t)(nt * 16 + l15) * 65536 + k8 + lg * 8];
        bf16x8 r0 = *(const bf16x8*)&relb[(size_t)(nt * 32 + l15) * 256 + k8 + lg * 8];
        bf16x8 r1 = *(const bf16x8*)&relb[(size_t)(nt * 32 + 16 + l15) * 256 + k8 + lg * 8];
        sacc = MFMA16(af, bf, sacc);
        e0 = MFMA16(af, r0, e0);
        e1 = MFMA16(af, r1, e1);
    }
#pragma unroll
    for (int r = 0; r < 4; ++r) {
        int row = mt * 16 + lg * 4 + r;
        ssc[row * 32 + nt * 16 + l15] = sacc[r];
        es[row * 64 + nt * 32 + l15] = e0[r];
        es[row * 64 + nt * 32 + 16 + l15] = e1[r];
    }
    __syncthreads();

    {
        int h = tid >> 3, sub = tid & 7;
        float v4[4];
        float mx = -1e30f;
#pragma unroll
        for (int i = 0; i < 4; ++i) {
            int k = sub * 4 + i;
            int dh = k - h; if (dh < 0) dh += 63;
            int dw = k - w; if (dw < 0) dw += 63;
            float s = (ssc[h * 32 + k] + es[h * 64 + dh] + es[h * 64 + dw]) * 0.0625f;
            v4[i] = s;
            mx = fmaxf(mx, s);
        }
        mx = fmaxf(mx, __shfl_xor(mx, 1));
        mx = fmaxf(mx, __shfl_xor(mx, 2));
        mx = fmaxf(mx, __shfl_xor(mx, 4));
        float sum = 0.f;
#pragma unroll
        for (int i = 0; i < 4; ++i) {
            v4[i] = __expf(v4[i] - mx);
            sum += v4[i];
        }
        sum += __shfl_xor(sum, 1);
        sum += __shfl_xor(sum, 2);
        sum += __shfl_xor(sum, 4);
        float inv = 1.f / sum;
#pragma unroll
        for (int i = 0; i < 4; ++i) ps[h * 32 + sub * 4 + i] = __float2bfloat16(v4[i] * inv);
    }
    __syncthreads();

    bf16x8 paf = *(const bf16x8*)&ps[(mt * 16 + l15) * 32 + lg * 8];
#pragma unroll
    for (int j = 0; j < 8; ++j) {
        int ct = nt * 8 + j;  // 0..15
        bf16x8 bv = *(const bf16x8*)&vt[(size_t)(ct * 16 + l15) * 40 + lg * 8];
        f32x4 oacc = {};
        oacc = MFMA16(paf, bv, oacc);
#pragma unroll
        for (int r = 0; r < 4; ++r) {
            int hh = mt * 16 + lg * 4 + r;
            O[rowbase + (size_t)hh * 65536 + ct * 16 + l15] = __float2bfloat16(oacc[r]);
        }
    }
}

// ---------------------------------------------------------------------------
extern "C" void kernel_launch(void* const* d_in, const int* in_sizes, int n_in, void* d_out,
                              int out_size, void* d_ws, size_t ws_size, hipStream_t stream) {
    const float* Xl = (const float*)d_in[0];
    const float* Xr = (const float*)d_in[1];
    const float* Wq = (const float*)d_in[2];
    const float* bq = (const float*)d_in[3];
    const float* Wk = (const float*)d_in[4];
    const float* bk = (const float*)d_in[5];
    const float* Wv = (const float*)d_in[6];
    const float* bv = (const float*)d_in[7];
    const float* Wo = (const float*)d_in[8];
    const float* bo = (const float*)d_in[9];
    const float* rel = (const float*)d_in[10];
    float* out = (float*)d_out;

    char* ws = (char*)d_ws;
    size_t off = 0;
    auto nxt = [&](size_t bytes) {
        void* p = ws + off;
        off += bytes;
        return p;
    };
    __hip_bfloat16* Xbl = (__hip_bfloat16*)nxt(16777216);
    __hip_bfloat16* Xbr = (__hip_bfloat16*)nxt(16777216);
    __hip_bfloat16* Wtq = (__hip_bfloat16*)nxt(8388608);
    __hip_bfloat16* Wtk = (__hip_bfloat16*)nxt(8388608);
    __hip_bfloat16* Wtv = (__hip_bfloat16*)nxt(8388608);
    __hip_bfloat16* Wto = (__hip_bfloat16*)nxt(8388608);
    __hip_bfloat16* relb = (__hip_bfloat16*)nxt(32768);
    __hip_bfloat16* Ql = (__hip_bfloat16*)nxt(16777216);
    __hip_bfloat16* Kl = (__hip_bfloat16*)nxt(16777216);
    __hip_bfloat16* Vl = (__hip_bfloat16*)nxt(16777216);
    __hip_bfloat16* Qr = (__hip_bfloat16*)nxt(16777216);
    __hip_bfloat16* Kr = (__hip_bfloat16*)nxt(16777216);
    __hip_bfloat16* Vr = (__hip_bfloat16*)nxt(16777216);
    // att outputs alias the Xb buffers (Xb dead after phase-1 GEMM)
    __hip_bfloat16* At0 = Xbl;
    __hip_bfloat16* At1 = Xbr;

    dim3 tb(32, 8);
    // X transposes also emit the raw-feature fp32 copy into the concat output
    transpose_x<<<dim3(32, 64, 4), tb, 0, stream>>>(Xl, Xbl, out);
    transpose_x<<<dim3(32, 64, 4), tb, 0, stream>>>(Xr, Xbr, out + 16777216);
    TArgs tw;
    tw.src[0] = Wq; tw.src[1] = Wk; tw.src[2] = Wv; tw.src[3] = Wo;
    tw.dst[0] = Wtq; tw.dst[1] = Wtk; tw.dst[2] = Wtv; tw.dst[3] = Wto;
    transpose_w4<<<dim3(64, 64, 4), tb, 0, stream>>>(tw);
    conv_rel<<<64, 256, 0, stream>>>(rel, relb);

    GArgs g1 = {};
    g1.A[0] = Xbl; g1.A[1] = Xbl; g1.A[2] = Xbl;
    g1.A[3] = Xbr; g1.A[4] = Xbr; g1.A[5] = Xbr;
    g1.B[0] = Wtq; g1.B[1] = Wtk; g1.B[2] = Wtv;
    g1.B[3] = Wtq; g1.B[4] = Wtk; g1.B[5] = Wtv;
    g1.C[0] = Ql; g1.C[1] = Kl; g1.C[2] = Vl;
    g1.C[3] = Qr; g1.C[4] = Kr; g1.C[5] = Vr;
    g1.bias[0] = bq; g1.bias[1] = bk; g1.bias[2] = bv;
    g1.bias[3] = bq; g1.bias[4] = bk; g1.bias[5] = bv;
    // M=4096/256=16, N=2048/128=16, z=6 -> 1536 blocks (3 rounds at 2/CU)
    gemmS<0><<<dim3(16, 16, 6), 256, 0, stream>>>(g1, 2048, 2048, nullptr);

    // dir0: weighted_r = attn(Q_l, K_r, V_r); dir1: weighted_l = attn(Q_r, K_l, V_l)
    attn_kernel<<<dim3(32, 8, 8), 256, 0, stream>>>(Ql, Kr, Vr, Qr, Kl, Vl, relb, At0, At1);

    // phase-2: A=Wo^T (n rows: 2048/256=8), B=att (m rows: 4096/128=32)
    GArgs g2 = {};
    g2.A[0] = Wto; g2.A[1] = Wto;
    g2.B[0] = At0; g2.B[1] = At1;
    g2.bias[0] = bo; g2.bias[1] = bo;
    gemmS<1><<<dim3(32, 8, 2), 256, 0, stream>>>(g2, 2048, 2048, out);
}

// Round 10
// 346.679 us; speedup vs baseline: 1.8889x; 1.0669x over previous
//
#include <hip/hip_runtime.h>
#include <hip/hip_bf16.h>

typedef __attribute__((ext_vector_type(8))) short bf16x8;
typedef __attribute__((ext_vector_type(4))) float f32x4;

#define MFMA16(a, b, c) __builtin_amdgcn_mfma_f32_16x16x32_bf16((a), (b), (c), 0, 0, 0)

typedef __attribute__((address_space(1))) const void gconst_t;
typedef __attribute__((address_space(3))) void lds_t;
__device__ __forceinline__ void gload16(const void* gp, void* lp) {
    __builtin_amdgcn_global_load_lds((gconst_t*)gp, (lds_t*)lp, 16, 0, 0);
}

#define BAR() asm volatile("s_barrier" ::: "memory")
#define VMCNT0() asm volatile("s_waitcnt vmcnt(0)" ::: "memory")
#define PRIO1() __builtin_amdgcn_s_setprio(1)
#define PRIO0() __builtin_amdgcn_s_setprio(0)
#define SCHED0() __builtin_amdgcn_sched_barrier(0)

// ---------------------------------------------------------------------------
// Transpose + cast fp32 -> bf16:  X tensors (R=2048, C=1024, z=4 batches),
// also writes the raw fp32 tile into the concat output's first 2048 channels.
// ---------------------------------------------------------------------------
__global__ void transpose_x(const float* __restrict__ in, __hip_bfloat16* __restrict__ out,
                            float* __restrict__ copy_out) {
    __shared__ float tile[32][33];
    int r0 = blockIdx.y * 32, c0 = blockIdx.x * 32;
    size_t zoff = (size_t)blockIdx.z * 2048 * 1024;
    const float* ib = in + zoff;
    __hip_bfloat16* ob = out + zoff;
    float* cb = copy_out + (size_t)blockIdx.z * 4194304;
    int tx = threadIdx.x, ty = threadIdx.y;
#pragma unroll
    for (int i = ty; i < 32; i += 8) {
        float v = ib[(size_t)(r0 + i) * 1024 + c0 + tx];
        tile[i][tx] = v;
        cb[(size_t)(r0 + i) * 1024 + c0 + tx] = v;
    }
    __syncthreads();
#pragma unroll
    for (int i = ty; i < 32; i += 8)
        ob[(size_t)(c0 + i) * 2048 + r0 + tx] = __float2bfloat16(tile[tx][i]);
}

// All four 2048x2048 weight transposes in one dispatch (z selects the matrix)
struct TArgs {
    const float* src[4];
    __hip_bfloat16* dst[4];
};
__global__ void transpose_w4(TArgs ta) {
    __shared__ float tile[32][33];
    const int z = blockIdx.z;
    const float* __restrict__ ib = ta.src[z];
    __hip_bfloat16* __restrict__ ob = ta.dst[z];
    int r0 = blockIdx.y * 32, c0 = blockIdx.x * 32;
    int tx = threadIdx.x, ty = threadIdx.y;
#pragma unroll
    for (int i = ty; i < 32; i += 8)
        tile[i][tx] = ib[(size_t)(r0 + i) * 2048 + c0 + tx];
    __syncthreads();
#pragma unroll
    for (int i = ty; i < 32; i += 8)
        ob[(size_t)(c0 + i) * 2048 + r0 + tx] = __float2bfloat16(tile[tx][i]);
}

// rel_emb (63x256 fp32) -> bf16 padded to 64 rows (row 63 = 0)
__global__ void conv_rel(const float* __restrict__ rel, __hip_bfloat16* __restrict__ relb) {
    int i = blockIdx.x * 256 + threadIdx.x;  // 64*256 = 16384
    if (i < 64 * 256) {
        int r = i >> 8;
        relb[i] = __float2bfloat16(r < 63 ? rel[i] : 0.f);
    }
}

// ---------------------------------------------------------------------------
// 256x256 tile, BK=64, 8 waves (2Mx4N, wave tile 128x64), 1 block/CU.
// m201-faithful quadrant rotation, SINGLE barrier per phase:
//   P1: rd aL,bL | stage A0,B0(t+1)->alt | BAR | MFMA(lo,lo)
//   P2: rd bH    | stage A1,B1(t+1)->alt | BAR | MFMA(lo,hi)
//   P3: rd aH    |                         BAR | MFMA(hi,hi)
//   P4:          | vmcnt(0) gate         | BAR | MFMA(hi,lo)   (bL reused)
// Reads issue right after the previous MFMA cluster -> LDS pipe drains under
// the matrix-pipe backlog (issue-level overlap, no extra frag registers:
// every set's WAR gap is >= 2 phases by rotation).  Single-barrier staging
// safety: a region's readers complete before their own MFMA, which precedes
// the barrier the stager has already passed.  Gate ~free (issued 2 phases =
// ~1300 cyc before drain > 900-cyc HBM latency).  Tail: tn=t-1 re-stages
// identical data into alt (same parity).  Frags 96 VGPR + acc 128 AGPR.
// ---------------------------------------------------------------------------
struct GArgs {
    const __hip_bfloat16* A[6];
    const __hip_bfloat16* B[6];
    void* C[6];
    const float* bias[6];
};

template <int MODE>
__global__ __launch_bounds__(512, 2) void gemm8p(GArgs ga, float* __restrict__ dout) {
    constexpr int K = 2048;
    constexpr int NOUT = 2048;
    constexpr int NT = 32;  // K / 64
    __shared__ __align__(16) char smem[131072];

    // XCD-aware chunked swizzle (nwg % 8 == 0 for all our launches)
    const int gx = gridDim.x, gy = gridDim.y;
    int lid = blockIdx.x + gx * (blockIdx.y + gy * blockIdx.z);
    const int nwg = gx * gy * gridDim.z;
    int swz = (lid & 7) * (nwg >> 3) + (lid >> 3);
    const int z = swz / (gx * gy);
    int rem = swz - z * (gx * gy);
    const int by = rem / gx;
    const int bx = rem - by * gx;

    const __hip_bfloat16* __restrict__ A = ga.A[z];
    const __hip_bfloat16* __restrict__ B = ga.B[z];
    const float* __restrict__ bias = ga.bias[z];
    const int row0 = by * 256, col0 = bx * 256;

    const int tid = threadIdx.x;
    const int wave = tid >> 6, lane = tid & 63;
    const int l15 = lane & 15, lg = lane >> 4;
    const int wm = wave >> 2, wn = wave & 3;  // 2x4 grid of 128x64 wave tiles

    // staging: 16B/thread/sweep; source chunk pre-swizzled (rule #21)
    const int srow = tid >> 3;               // 0..63 row within 64-row sweep
    const int sch = (tid & 7) ^ (srow & 7);  // swizzled source chunk
    // read-side XOR (proven zero-conflict layout)
    const int xr = (l15 & 7) << 4;
    const int off0 = (lg * 16) ^ xr;
    const int off1 = (64 + lg * 16) ^ xr;

    f32x4 acc[8][4] = {};
    bf16x8 aL[4][2], aH[4][2], bL[2][2], bH[2][2];

    // stage one 128-row half (h) of A (isB=0) or B (isB=1) of K-tile T -> buf
    auto ST = [&](const __hip_bfloat16* base, int rowb, int T, int buf, int isB, int h) {
#pragma unroll
        for (int L = 0; L < 2; ++L)
            gload16(base + (size_t)(rowb + h * 128 + L * 64 + srow) * K + T * 64 + sch * 8,
                    smem + buf * 65536 + isB * 32768 + h * 16384 + L * 8192 + tid * 16);
    };

#define RD_A(DST, C, MH)                                                           \
    _Pragma("unroll") for (int mf = 0; mf < 4; ++mf) {                             \
        const char* p = smem + (C) * 65536 + (wm * 128 + (MH) * 64 + mf * 16 + l15) * 128; \
        DST[mf][0] = *(const bf16x8*)(p + off0);                                   \
        DST[mf][1] = *(const bf16x8*)(p + off1);                                   \
    }
#define RD_B(DST, C, NH)                                                           \
    _Pragma("unroll") for (int nf = 0; nf < 2; ++nf) {                             \
        const char* p = smem + (C) * 65536 + 32768 +                               \
                        (wn * 64 + (NH) * 32 + nf * 16 + l15) * 128;               \
        DST[nf][0] = *(const bf16x8*)(p + off0);                                   \
        DST[nf][1] = *(const bf16x8*)(p + off1);                                   \
    }
#define MQ(MH, NH, AR, BR)                                                         \
    SCHED0();                                                                      \
    PRIO1();                                                                       \
    _Pragma("unroll") for (int mf = 0; mf < 4; ++mf)                               \
    _Pragma("unroll") for (int nf = 0; nf < 2; ++nf) {                             \
        acc[(MH)*4 + mf][(NH)*2 + nf] =                                            \
            MFMA16(AR[mf][0], BR[nf][0], acc[(MH)*4 + mf][(NH)*2 + nf]);           \
        acc[(MH)*4 + mf][(NH)*2 + nf] =                                            \
            MFMA16(AR[mf][1], BR[nf][1], acc[(MH)*4 + mf][(NH)*2 + nf]);           \
    }                                                                              \
    PRIO0();

#define KTILE(T, C)                                          \
    {                                                        \
        const int tn = ((T) + 1 < NT) ? (T) + 1 : (T)-1;     \
        /* P1 */                                             \
        RD_A(aL, C, 0);                                      \
        RD_B(bL, C, 0);                                      \
        ST(A, row0, tn, (C) ^ 1, 0, 0);                      \
        ST(B, col0, tn, (C) ^ 1, 1, 0);                      \
        BAR();                                               \
        MQ(0, 0, aL, bL);                                    \
        /* P2 */                                             \
        RD_B(bH, C, 1);                                      \
        ST(A, row0, tn, (C) ^ 1, 0, 1);                      \
        ST(B, col0, tn, (C) ^ 1, 1, 1);                      \
        BAR();                                               \
        MQ(0, 1, aL, bH);                                    \
        /* P3 */                                             \
        RD_A(aH, C, 1);                                      \
        BAR();                                               \
        MQ(1, 1, aH, bH);                                    \
        /* P4 */                                             \
        VMCNT0();                                            \
        BAR();                                               \
        MQ(1, 0, aH, bL);                                    \
    }

    // prologue: tile 0 fully staged into buf0
    ST(A, row0, 0, 0, 0, 0);
    ST(A, row0, 0, 0, 0, 1);
    ST(B, col0, 0, 0, 1, 0);
    ST(B, col0, 0, 0, 1, 1);
    VMCNT0();
    BAR();

#pragma unroll 1
    for (int t = 0; t < NT; t += 2) {
        KTILE(t, 0);
        KTILE(t + 1, 1);
    }

    if (MODE == 0) {
        __hip_bfloat16* __restrict__ C = (__hip_bfloat16*)ga.C[z];
#pragma unroll
        for (int mf = 0; mf < 8; ++mf) {
            int m = row0 + wm * 128 + mf * 16 + lg * 4;
#pragma unroll
            for (int nf = 0; nf < 4; ++nf) {
                int n = col0 + wn * 64 + nf * 16 + l15;
                float bv = bias[n];
#pragma unroll
                for (int r = 0; r < 4; ++r)
                    C[(size_t)(m + r) * NOUT + n] = __float2bfloat16(acc[mf][nf][r] + bv);
            }
        }
    } else {
        // rows = output channel n, cols = m = b*1024 + p (coalesced in p)
        float* __restrict__ OB = dout + (size_t)z * 16777216;
#pragma unroll
        for (int mf = 0; mf < 8; ++mf) {
            int n0 = row0 + wm * 128 + mf * 16 + lg * 4;
#pragma unroll
            for (int nf = 0; nf < 4; ++nf) {
                int m = col0 + wn * 64 + nf * 16 + l15;
                size_t base = (size_t)(m >> 10) * 4194304 + (size_t)(m & 1023);
#pragma unroll
                for (int r = 0; r < 4; ++r) {
                    int n = n0 + r;
                    OB[base + (size_t)(2048 + n) * 1024] = acc[mf][nf][r] + bias[n];
                }
            }
        }
    }
#undef RD_A
#undef RD_B
#undef MQ
#undef KTILE
}

// ---------------------------------------------------------------------------
// Axial attention: one block per (dir, b, head, w).  Q,K,V row-major [4096][2048] bf16.
// ---------------------------------------------------------------------------
__global__ __launch_bounds__(256, 2) void attn_kernel(
    const __hip_bfloat16* __restrict__ Qa, const __hip_bfloat16* __restrict__ Ka,
    const __hip_bfloat16* __restrict__ Va, const __hip_bfloat16* __restrict__ Qb,
    const __hip_bfloat16* __restrict__ Kb, const __hip_bfloat16* __restrict__ Vb,
    const __hip_bfloat16* __restrict__ relb, __hip_bfloat16* __restrict__ Oa,
    __hip_bfloat16* __restrict__ Ob) {
    const int w = blockIdx.x;   // 0..31
    const int nh = blockIdx.y;  // 0..7
    const int zb = blockIdx.z;  // dir*4 + b
    const int dir = zb >> 2, b = zb & 3;
    const __hip_bfloat16* __restrict__ Q = dir ? Qb : Qa;
    const __hip_bfloat16* __restrict__ K = dir ? Kb : Ka;
    const __hip_bfloat16* __restrict__ V = dir ? Vb : Va;
    __hip_bfloat16* __restrict__ O = dir ? Ob : Oa;

    __shared__ __align__(16) __hip_bfloat16 vt[256 * 40];  // V^T, stride 40
    __shared__ float ssc[32 * 32];
    __shared__ float es[32 * 64];
    __shared__ __align__(16) __hip_bfloat16 ps[32 * 32];

    const int tid = threadIdx.x;
    const int lane = tid & 63, wave = tid >> 6;
    const int l15 = lane & 15, lg = lane >> 4;
    const int mt = wave >> 1, nt = wave & 1;

    const size_t rowbase = ((size_t)b * 1024 + w) * 2048 + (size_t)nh * 256;

    // stage V transposed: vt[c][hk]
    for (int i = 0; i < 32; ++i) {
        int e = i * 256 + tid;
        int hk = e >> 8, c = e & 255;
        vt[c * 40 + hk] = V[rowbase + (size_t)hk * 65536 + c];
    }

    f32x4 sacc = {}, e0 = {}, e1 = {};
#pragma unroll
    for (int k8 = 0; k8 < 256; k8 += 32) {
        bf16x8 af = *(const bf16x8*)&Q[rowbase + (size_t)(mt * 16 + l15) * 65536 + k8 + lg * 8];
        bf16x8 bf = *(const bf16x8*)&K[rowbase + (size_t)(nt * 16 + l15) * 65536 + k8 + lg * 8];
        bf16x8 r0 = *(const bf16x8*)&relb[(size_t)(nt * 32 + l15) * 256 + k8 + lg * 8];
        bf16x8 r1 = *(const bf16x8*)&relb[(size_t)(nt * 32 + 16 + l15) * 256 + k8 + lg * 8];
        sacc = MFMA16(af, bf, sacc);
        e0 = MFMA16(af, r0, e0);
        e1 = MFMA16(af, r1, e1);
    }
#pragma unroll
    for (int r = 0; r < 4; ++r) {
        int row = mt * 16 + lg * 4 + r;
        ssc[row * 32 + nt * 16 + l15] = sacc[r];
        es[row * 64 + nt * 32 + l15] = e0[r];
        es[row * 64 + nt * 32 + 16 + l15] = e1[r];
    }
    __syncthreads();

    {
        int h = tid >> 3, sub = tid & 7;
        float v4[4];
        float mx = -1e30f;
#pragma unroll
        for (int i = 0; i < 4; ++i) {
            int k = sub * 4 + i;
            int dh = k - h; if (dh < 0) dh += 63;
            int dw = k - w; if (dw < 0) dw += 63;
            float s = (ssc[h * 32 + k] + es[h * 64 + dh] + es[h * 64 + dw]) * 0.0625f;
            v4[i] = s;
            mx = fmaxf(mx, s);
        }
        mx = fmaxf(mx, __shfl_xor(mx, 1));
        mx = fmaxf(mx, __shfl_xor(mx, 2));
        mx = fmaxf(mx, __shfl_xor(mx, 4));
        float sum = 0.f;
#pragma unroll
        for (int i = 0; i < 4; ++i) {
            v4[i] = __expf(v4[i] - mx);
            sum += v4[i];
        }
        sum += __shfl_xor(sum, 1);
        sum += __shfl_xor(sum, 2);
        sum += __shfl_xor(sum, 4);
        float inv = 1.f / sum;
#pragma unroll
        for (int i = 0; i < 4; ++i) ps[h * 32 + sub * 4 + i] = __float2bfloat16(v4[i] * inv);
    }
    __syncthreads();

    bf16x8 paf = *(const bf16x8*)&ps[(mt * 16 + l15) * 32 + lg * 8];
#pragma unroll
    for (int j = 0; j < 8; ++j) {
        int ct = nt * 8 + j;  // 0..15
        bf16x8 bv = *(const bf16x8*)&vt[(size_t)(ct * 16 + l15) * 40 + lg * 8];
        f32x4 oacc = {};
        oacc = MFMA16(paf, bv, oacc);
#pragma unroll
        for (int r = 0; r < 4; ++r) {
            int hh = mt * 16 + lg * 4 + r;
            O[rowbase + (size_t)hh * 65536 + ct * 16 + l15] = __float2bfloat16(oacc[r]);
        }
    }
}

// ---------------------------------------------------------------------------
extern "C" void kernel_launch(void* const* d_in, const int* in_sizes, int n_in, void* d_out,
                              int out_size, void* d_ws, size_t ws_size, hipStream_t stream) {
    const float* Xl = (const float*)d_in[0];
    const float* Xr = (const float*)d_in[1];
    const float* Wq = (const float*)d_in[2];
    const float* bq = (const float*)d_in[3];
    const float* Wk = (const float*)d_in[4];
    const float* bk = (const float*)d_in[5];
    const float* Wv = (const float*)d_in[6];
    const float* bv = (const float*)d_in[7];
    const float* Wo = (const float*)d_in[8];
    const float* bo = (const float*)d_in[9];
    const float* rel = (const float*)d_in[10];
    float* out = (float*)d_out;

    char* ws = (char*)d_ws;
    size_t off = 0;
    auto nxt = [&](size_t bytes) {
        void* p = ws + off;
        off += bytes;
        return p;
    };
    __hip_bfloat16* Xbl = (__hip_bfloat16*)nxt(16777216);
    __hip_bfloat16* Xbr = (__hip_bfloat16*)nxt(16777216);
    __hip_bfloat16* Wtq = (__hip_bfloat16*)nxt(8388608);
    __hip_bfloat16* Wtk = (__hip_bfloat16*)nxt(8388608);
    __hip_bfloat16* Wtv = (__hip_bfloat16*)nxt(8388608);
    __hip_bfloat16* Wto = (__hip_bfloat16*)nxt(8388608);
    __hip_bfloat16* relb = (__hip_bfloat16*)nxt(32768);
    __hip_bfloat16* Ql = (__hip_bfloat16*)nxt(16777216);
    __hip_bfloat16* Kl = (__hip_bfloat16*)nxt(16777216);
    __hip_bfloat16* Vl = (__hip_bfloat16*)nxt(16777216);
    __hip_bfloat16* Qr = (__hip_bfloat16*)nxt(16777216);
    __hip_bfloat16* Kr = (__hip_bfloat16*)nxt(16777216);
    __hip_bfloat16* Vr = (__hip_bfloat16*)nxt(16777216);
    // att outputs alias the Xb buffers (Xb dead after phase-1 GEMM)
    __hip_bfloat16* At0 = Xbl;
    __hip_bfloat16* At1 = Xbr;

    dim3 tb(32, 8);
    // X transposes also emit the raw-feature fp32 copy into the concat output
    transpose_x<<<dim3(32, 64, 4), tb, 0, stream>>>(Xl, Xbl, out);
    transpose_x<<<dim3(32, 64, 4), tb, 0, stream>>>(Xr, Xbr, out + 16777216);
    TArgs tw;
    tw.src[0] = Wq; tw.src[1] = Wk; tw.src[2] = Wv; tw.src[3] = Wo;
    tw.dst[0] = Wtq; tw.dst[1] = Wtk; tw.dst[2] = Wtv; tw.dst[3] = Wto;
    transpose_w4<<<dim3(64, 64, 4), tb, 0, stream>>>(tw);
    conv_rel<<<64, 256, 0, stream>>>(rel, relb);

    GArgs g1 = {};
    g1.A[0] = Xbl; g1.A[1] = Xbl; g1.A[2] = Xbl;
    g1.A[3] = Xbr; g1.A[4] = Xbr; g1.A[5] = Xbr;
    g1.B[0] = Wtq; g1.B[1] = Wtk; g1.B[2] = Wtv;
    g1.B[3] = Wtq; g1.B[4] = Wtk; g1.B[5] = Wtv;
    g1.C[0] = Ql; g1.C[1] = Kl; g1.C[2] = Vl;
    g1.C[3] = Qr; g1.C[4] = Kr; g1.C[5] = Vr;
    g1.bias[0] = bq; g1.bias[1] = bk; g1.bias[2] = bv;
    g1.bias[3] = bq; g1.bias[4] = bk; g1.bias[5] = bv;
    // M=4096/256=16, N=2048/256=8, z=6 -> 768 blocks (3 rounds at 1/CU)
    gemm8p<0><<<dim3(8, 16, 6), 512, 0, stream>>>(g1, nullptr);

    // dir0: weighted_r = attn(Q_l, K_r, V_r); dir1: weighted_l = attn(Q_r, K_l, V_l)
    attn_kernel<<<dim3(32, 8, 8), 256, 0, stream>>>(Ql, Kr, Vr, Qr, Kl, Vl, relb, At0, At1);

    // phase-2: A=Wo^T (2048/256=8 row-blocks), B=att (4096/256=16)
    GArgs g2 = {};
    g2.A[0] = Wto; g2.A[1] = Wto;
    g2.B[0] = At0; g2.B[1] = At1;
    g2.bias[0] = bo; g2.bias[1] = bo;
    gemm8p<1><<<dim3(16, 8, 2), 512, 0, stream>>>(g2, out);
}